// Round 16
// baseline (443.815 us; speedup 1.0000x reference)
//
#include <hip/hip_runtime.h>
#include <math.h>

#define ALPHA_ 0.1f
#define BETA_  0.9f
#define EPS_   1e-5f

typedef __bf16 bf16x8 __attribute__((ext_vector_type(8)));
typedef float f32x16 __attribute__((ext_vector_type(16)));

__device__ __forceinline__ unsigned short f2bf(float f) {
    return __builtin_bit_cast(unsigned short, (__bf16)f);
}
__device__ __forceinline__ float bf2f(unsigned short u) {
    return (float)__builtin_bit_cast(__bf16, u);
}

__device__ __forceinline__ float wave_reduce_sum(float v) {
#pragma unroll
    for (int off = 32; off > 0; off >>= 1) v += __shfl_down(v, off, 64);
    return v;
}

// ---------------- LN partial sums (per-b mean/var, stage 1) ----------------
__global__ void k_ln_part(const float4* __restrict__ x4, float2* __restrict__ part) {
    const int b = blockIdx.y, jb = blockIdx.x, t = threadIdx.x;
    const size_t base = (size_t)b * 307200 + (size_t)jb * 4096;
    float s = 0.f, sq = 0.f;
#pragma unroll
    for (int k = 0; k < 16; k++) {
        float4 v = x4[base + k * 256 + t];
        s  += v.x + v.y + v.z + v.w;
        sq += v.x * v.x + v.y * v.y + v.z * v.z + v.w * v.w;
    }
    float rs = wave_reduce_sum(s);
    float rq = wave_reduce_sum(sq);
    __shared__ float2 ws[4];
    if ((t & 63) == 0) ws[t >> 6] = make_float2(rs, rq);
    __syncthreads();
    if (t == 0) {
        float a = 0.f, q = 0.f;
        for (int k = 0; k < 4; k++) { a += ws[k].x; q += ws[k].y; }
        part[b * 75 + jb] = make_float2(a, q);
    }
}

__global__ void k_ln_final(const float2* __restrict__ part, int nper, float2* __restrict__ outp) {
    const int b = blockIdx.x, t = threadIdx.x;
    float s = 0.f, sq = 0.f;
    for (int p = t; p < nper; p += 64) {
        float2 v = part[b * nper + p];
        s += v.x; sq += v.y;
    }
    s  = wave_reduce_sum(s);
    sq = wave_reduce_sum(sq);
    if (t == 0) {
        const float invN = 1.f / 1228800.f;
        float mu  = s * invN;
        float var = sq * invN - mu * mu;
        outp[b] = make_float2(mu, rsqrtf(var + EPS_));
    }
}

// ---------------- fused GRU: LN1 + input proj + recurrence ----------------
__global__ __launch_bounds__(512) void k_gru3(const float* __restrict__ x,
        const float* __restrict__ g1, const float* __restrict__ b1,
        const float2* __restrict__ s1, const float* __restrict__ Wih,
        const float* __restrict__ Whh, const float* __restrict__ bih,
        const float* __restrict__ bhh, float* __restrict__ xr, float2* __restrict__ s2p) {
    __shared__ unsigned short hb[32 * 128];
    __shared__ float gh[8 * 192];
    __shared__ float ghn[8 * 64];
    __shared__ float2 sRed[8];
    const int t = threadIdx.x;
    const int wid = t >> 6, lane = t & 63, ln = lane & 31, hl = lane >> 5;
    const int row0 = blockIdx.x * 8;
    const int r = wid;
    const int c = t & 63;
    const int row = row0 + r;
    const int sd = row % 200;
    const int bidx = row / 200;
    const bool isN = (wid >= 4 && wid < 6);

    bf16x8 Bf[8];
    if (wid < 6) {
        const int j = wid * 32 + ln;
#pragma unroll
        for (int ks = 0; ks < 8; ks++) {
            const float* Wsrc = (ks < 4) ? Wih : Whh;
            const int kk = (ks & 3) * 16 + hl * 8;
            const float* wp = Wsrc + j * 64 + kk;
            float4 w0 = *(const float4*)wp;
            float4 w1 = *(const float4*)(wp + 4);
            bf16x8 bb;
            bb[0] = (__bf16)w0.x; bb[1] = (__bf16)w0.y; bb[2] = (__bf16)w0.z; bb[3] = (__bf16)w0.w;
            bb[4] = (__bf16)w1.x; bb[5] = (__bf16)w1.y; bb[6] = (__bf16)w1.z; bb[7] = (__bf16)w1.w;
            Bf[ks] = bb;
        }
    }
    for (int i = t; i < 4096; i += 512) hb[i] = 0;
    __syncthreads();

    const float b_r = bih[c] + bhh[c];
    const float b_z = bih[64 + c] + bhh[64 + c];
    const float bx_n = bih[128 + c];
    const float bh_n = bhh[128 + c];
    const float2 st1 = s1[bidx];
    const float* xp  = x  + (size_t)row * 96 * 64;
    const float* gp  = g1 + (size_t)sd * 96 * 64;
    const float* bp  = b1 + (size_t)sd * 96 * 64;
    float*       xrp = xr + (size_t)row * 96 * 64;

    float xv = xp[c];
    {
        float xln = (xv - st1.x) * st1.y * gp[c] + bp[c];
        *(unsigned short*)((char*)hb + ((r * 256 + c * 2) ^ ((r & 7) << 4))) = f2bf(xln);
    }
    float h = 0.f, lsum = 0.f, lsq = 0.f;
    __syncthreads();

    for (int st = 0; st < 96; st++) {
        if (wid < 4) {
            f32x16 acc = {};
#pragma unroll
            for (int ks = 0; ks < 8; ks++) {
                int ao = (ln * 256 + ks * 32 + hl * 16) ^ ((ln & 7) << 4);
                bf16x8 af = __builtin_bit_cast(bf16x8, *(const uint4*)((const char*)hb + ao));
                acc = __builtin_amdgcn_mfma_f32_32x32x16_bf16(af, Bf[ks], acc, 0, 0, 0);
            }
#pragma unroll
            for (int reg = 0; reg < 4; reg++)
                gh[(reg + 4 * hl) * 192 + wid * 32 + ln] = acc[reg];
        } else if (isN) {
            f32x16 accx = {}, acch = {};
#pragma unroll
            for (int ks = 0; ks < 4; ks++) {
                int aox = (ln * 256 + ks * 32 + hl * 16) ^ ((ln & 7) << 4);
                bf16x8 afx = __builtin_bit_cast(bf16x8, *(const uint4*)((const char*)hb + aox));
                accx = __builtin_amdgcn_mfma_f32_32x32x16_bf16(afx, Bf[ks], accx, 0, 0, 0);
                int aoh = (ln * 256 + (ks + 4) * 32 + hl * 16) ^ ((ln & 7) << 4);
                bf16x8 afh = __builtin_bit_cast(bf16x8, *(const uint4*)((const char*)hb + aoh));
                acch = __builtin_amdgcn_mfma_f32_32x32x16_bf16(afh, Bf[ks + 4], acch, 0, 0, 0);
            }
#pragma unroll
            for (int reg = 0; reg < 4; reg++) {
                gh[(reg + 4 * hl) * 192 + wid * 32 + ln] = accx[reg];
                ghn[(reg + 4 * hl) * 64 + (wid - 4) * 32 + ln] = acch[reg];
            }
        }
        int sn = st < 95 ? st + 1 : 95;
        float xv_n = xp[sn * 64 + c];
        float g1_n = gp[sn * 64 + c];
        float b1_n = bp[sn * 64 + c];
        __syncthreads();
        float rg_ = 1.f / (1.f + __expf(-(gh[r * 192 + c] + b_r)));
        float zg_ = 1.f / (1.f + __expf(-(gh[r * 192 + 64 + c] + b_z)));
        float xn = gh[r * 192 + 128 + c] + bx_n;
        float hn = ghn[r * 64 + c] + bh_n;
        float ny = xn + rg_ * hn;
        ny = fminf(fmaxf(ny, -15.f), 15.f);
        float e2 = __expf(-2.f * ny);
        float nv = (1.f - e2) / (1.f + e2);
        h = nv + zg_ * (h - nv);
        float ov = h + xv;
        xrp[st * 64 + c] = ov;
        lsum += ov; lsq += ov * ov;
        *(unsigned short*)((char*)hb + ((r * 256 + (64 + c) * 2) ^ ((r & 7) << 4))) = f2bf(h);
        float xln = (xv_n - st1.x) * st1.y * g1_n + b1_n;
        *(unsigned short*)((char*)hb + ((r * 256 + c * 2) ^ ((r & 7) << 4))) = f2bf(xln);
        xv = xv_n;
        __syncthreads();
    }
    float s = wave_reduce_sum(lsum);
    float q = wave_reduce_sum(lsq);
    if (lane == 0) sRed[wid] = make_float2(s, q);
    __syncthreads();
    if (t == 0) {
        float a = 0.f, b_ = 0.f;
        for (int k = 0; k < 8; k++) { a += sRed[k].x; b_ += sRed[k].y; }
        s2p[blockIdx.x] = make_float2(a, b_);
    }
}

// ---------------- transpose g2/b2: [64][200][96] -> [96][200][64] ----------------
__global__ void k_tr(const float* __restrict__ in, float* __restrict__ outp) {
    __shared__ float tile[32][33];
    const int v = blockIdx.x;
    const int ct = blockIdx.y & 1;
    const int lt = blockIdx.y >> 1;
    const int t = threadIdx.x;
    const int lx = t & 31, ly = t >> 5;
    const int c0 = ct * 32, l0 = lt * 32;
#pragma unroll
    for (int q = 0; q < 4; q++) {
        int cc = ly + q * 8;
        tile[cc][lx] = in[(size_t)(c0 + cc) * 19200 + (size_t)v * 96 + l0 + lx];
    }
    __syncthreads();
#pragma unroll
    for (int q = 0; q < 4; q++) {
        int ll = ly + q * 8;
        outp[(size_t)(l0 + ll) * 12800 + (size_t)v * 64 + c0 + lx] = tile[lx][ll];
    }
}

// ---------------- static adjacency -> normalized bf16, chunk-major [26][200][8] ----------------
__global__ void k_adjprep2(const float* __restrict__ adj, unsigned short* __restrict__ an_b,
        unsigned short* __restrict__ atn_b) {
    const int v = blockIdx.x;
    const int mode = blockIdx.y;
    const int t = threadIdx.x;
    unsigned short* outp = (mode == 0) ? an_b : atn_b;
    float val = 0.f;
    if (t < 200) val = (mode == 0) ? adj[v * 200 + t] : adj[t * 200 + v];
    float s = wave_reduce_sum(val);
    __shared__ float sp[4];
    if ((t & 63) == 0) sp[t >> 6] = s;
    __syncthreads();
    float inv = 1.f / (sp[0] + sp[1] + sp[2] + sp[3] + 1.f);
    if (t < 208) {
        float o = (t < 200) ? (val + (t == v ? 1.f : 0.f)) * inv : 0.f;
        outp[(((t >> 3) * 200) + v) * 8 + (t & 7)] = f2bf(o);
    }
}

// ---------------- dyna prep v5: 1024 threads, chunk-major output ----------------
__global__ __launch_bounds__(1024) void k_dprep5(const float* __restrict__ dyna,
        unsigned short* __restrict__ danr, unsigned short* __restrict__ danc) {
    __shared__ unsigned short sT[200 * 201];
    __shared__ float sRow[200];
    __shared__ float sColP[16][256];
    __shared__ float sInv[416];
    const int blk = blockIdx.x;
    const int t = threadIdx.x;
    const int lane = t & 63, rq = t >> 6;
    const float* S = dyna + (size_t)blk * 40000;
    float colacc[4] = {0.f, 0.f, 0.f, 0.f};
    for (int p = 0; p < 13; p++) {
        const int r = p * 16 + rq;
        if (r < 200) {
            float rsum = 0.f;
#pragma unroll
            for (int s = 0; s < 4; s++) {
                const int c = s * 64 + lane;
                if (c < 200) {
                    float v = S[r * 200 + c] + ((r == c) ? 1.f : 0.f);
                    sT[c * 201 + r] = f2bf(v);
                    rsum += v;
                    colacc[s] += v;
                }
            }
            float rs = wave_reduce_sum(rsum);
            if (lane == 0) sRow[r] = rs;
        }
    }
#pragma unroll
    for (int s = 0; s < 4; s++) sColP[rq][s * 64 + lane] = colacc[s];
    __syncthreads();
    if (t < 200) {
        sInv[t] = 1.f / sRow[t];
        float cs = 0.f;
#pragma unroll
        for (int q = 0; q < 16; q++) cs += sColP[q][t];
        sInv[208 + t] = 1.f / cs;
    }
    __syncthreads();
    unsigned short* dr = danr + (size_t)blk * 41600;
    unsigned short* dc = danc + (size_t)blk * 41600;
    for (int item = t; item < 5200; item += 1024) {
        const int cch = item / 200;
        const int v = item - cch * 200;
        const float irv = sInv[v];
        const float icv = sInv[208 + v];
        unsigned short rb[8], cb[8];
#pragma unroll
        for (int j = 0; j < 8; j++) {
            const int w = cch * 8 + j;
            float fr = 0.f, fc = 0.f;
            if (w < 200) {
                fr = bf2f(sT[w * 201 + v]) * irv;
                fc = bf2f(sT[v * 201 + w]) * icv;
            }
            rb[j] = f2bf(fr); cb[j] = f2bf(fc);
        }
        *(uint4*)&dr[item * 8] = make_uint4(
            (unsigned)rb[0] | ((unsigned)rb[1] << 16), (unsigned)rb[2] | ((unsigned)rb[3] << 16),
            (unsigned)rb[4] | ((unsigned)rb[5] << 16), (unsigned)rb[6] | ((unsigned)rb[7] << 16));
        *(uint4*)&dc[item * 8] = make_uint4(
            (unsigned)cb[0] | ((unsigned)cb[1] << 16), (unsigned)cb[2] | ((unsigned)cb[3] << 16),
            (unsigned)cb[4] | ((unsigned)cb[5] << 16), (unsigned)cb[6] | ((unsigned)cb[7] << 16));
    }
}

// ---------------- effective projection matrices (f32 scratch) + biasE ----------------
__global__ void k_meff(const float* __restrict__ Wm, const float* __restrict__ Wg1,
        const float* __restrict__ Wg2, const float* __restrict__ Wd1, const float* __restrict__ Wd2,
        const float* __restrict__ bg1, const float* __restrict__ bg2, const float* __restrict__ bd1,
        const float* __restrict__ bd2, const float* __restrict__ bm,
        float* __restrict__ MeffF, float* __restrict__ biasE) {
    const int k = blockIdx.x;
    const int t = threadIdx.x;
    const int o = t >> 2;
    const int cb = (t & 3) * 16;
    float acc[16];
#pragma unroll
    for (int q = 0; q < 16; q++) acc[q] = 0.f;
    if (k == 0) {
        for (int m = 0; m < 64; m++) {
            float aL = Wm[o * 128 + m], aR = Wm[o * 128 + 64 + m];
#pragma unroll
            for (int q = 0; q < 16; q++) {
                int cc = cb + q;
                acc[q] += aL * (Wg1[m * 192 + cc] + Wg2[m * 192 + cc])
                        + aR * (Wd1[m * 192 + cc] + Wd2[m * 192 + cc]);
            }
        }
    } else {
        const float* Ws = (k <= 2) ? Wg1 : (k <= 4) ? Wg2 : (k <= 6) ? Wd1 : Wd2;
        const int side = (k <= 4) ? 0 : 64;
        const int hop = (((k - 1) & 1) == 0) ? 64 : 128;
        for (int m = 0; m < 64; m++) {
            float a_ = Wm[o * 128 + side + m];
#pragma unroll
            for (int q = 0; q < 16; q++) acc[q] += a_ * Ws[m * 192 + hop + cb + q];
        }
    }
#pragma unroll
    for (int q = 0; q < 16; q++) MeffF[k * 4096 + o * 64 + cb + q] = acc[q];
    if (k == 0 && t < 64) {
        float s = bm[t];
        for (int cc = 0; cc < 64; cc++)
            s += Wm[t * 128 + cc] * (bg1[cc] + bg2[cc]) + Wm[t * 128 + 64 + cc] * (bd1[cc] + bd2[cc]);
        biasE[t] = s;
    }
}

// ---------------- combine: M_fold / N1 / N2 -> bf16 MeffB[9][4096] ----------------
__global__ void k_meffc(const float* __restrict__ MeffF, unsigned short* __restrict__ MeffB) {
    const int t = threadIdx.x;
#pragma unroll 4
    for (int j = 0; j < 16; j++) {
        int idx = t * 16 + j;
        float m[9];
#pragma unroll
        for (int k = 0; k < 9; k++) m[k] = MeffF[k * 4096 + idx];
        float sum = 0.f;
#pragma unroll
        for (int k = 1; k < 9; k++) sum += m[k];
        MeffB[idx] = f2bf(m[0] + ALPHA_ * sum);
#pragma unroll
        for (int c = 0; c < 4; c++) {
            MeffB[(1 + 2 * c) * 4096 + idx] = f2bf(BETA_ * m[1 + 2 * c] + ALPHA_ * BETA_ * m[2 + 2 * c]);
            MeffB[(2 + 2 * c) * 4096 + idx] = f2bf(BETA_ * BETA_ * m[2 + 2 * c]);
        }
    }
}

// ---------------- nx (bf16) = LN2(xr), layout [b*96+l][v][c] ----------------
__global__ void k_nx(const float4* __restrict__ xr4, const float2* __restrict__ s2,
        const float4* __restrict__ g2t4, const float4* __restrict__ b2t4,
        unsigned short* __restrict__ nxb) {
    size_t id = (size_t)blockIdx.x * 256 + threadIdx.x;
    int cf = (int)(id & 15);
    size_t grp = id >> 4;
    int v = (int)(grp % 200);
    size_t bl = grp / 200;
    int l = (int)(bl % 96);
    int b = (int)(bl / 96);
    float2 st = s2[b];
    float4 xv = xr4[(((size_t)(b * 200 + v)) * 96 + l) * 16 + cf];
    size_t gi = ((size_t)l * 200 + v) * 16 + cf;
    float4 g = g2t4[gi];
    float4 bb = b2t4[gi];
    unsigned int lo = (unsigned)f2bf((xv.x - st.x) * st.y * g.x + bb.x)
                    | ((unsigned)f2bf((xv.y - st.x) * st.y * g.y + bb.y) << 16);
    unsigned int hi = (unsigned)f2bf((xv.z - st.x) * st.y * g.z + bb.z)
                    | ((unsigned)f2bf((xv.w - st.x) * st.y * g.w + bb.w) << 16);
    ((uint2*)nxb)[id] = make_uint2(lo, hi);
}

// ================= MFMA graph kernel v12: 7 waves x 2 ot-tiles (shared A-fragment) =================
#define OFF_A 0
#define OFF_HTA 83968
#define OFF_HTB 110592
#define OFF_OBUF 0
#define SMEM10 137216

__device__ __forceinline__ int ht4(int o, int w) {
    return (o * 416 + w * 2) ^ ((o & 7) << 4);
}

__device__ __forceinline__ void store_tile_bf16(unsigned char* smem, int off, const f32x16& val,
        int mt, int ocol, int half) {
#pragma unroll
    for (int g = 0; g < 4; g++) {
        const int wv = mt * 32 + half * 4 + g * 8;
        if (wv < 200) {
            unsigned short pk[4];
#pragma unroll
            for (int i = 0; i < 4; i++) pk[i] = f2bf(val[g * 4 + i]);
            *(uint2*)(smem + off + ht4(ocol, wv)) = make_uint2(
                (unsigned)pk[0] | ((unsigned)pk[1] << 16),
                (unsigned)pk[2] | ((unsigned)pk[3] << 16));
        }
    }
}

__device__ __forceinline__ void stageA(const unsigned short* __restrict__ A,
        unsigned char* smem, int t) {
#pragma unroll
    for (int i = 0; i < 5; i++) {
        const int idx = t + i * 1024;
        __builtin_amdgcn_global_load_lds(
            (const __attribute__((address_space(1))) unsigned int*)(const void*)(A + (size_t)idx * 8),
            (__attribute__((address_space(3))) unsigned int*)(void*)(smem + OFF_A + idx * 16),
            16, 0, 0);
    }
    if (t < 80) {
        const int idx = 5120 + t;
        *(uint4*)(smem + OFF_A + idx * 16) = *(const uint4*)(const void*)(A + (size_t)idx * 8);
    }
}

__global__ __launch_bounds__(1024) void k_graph12(const unsigned short* __restrict__ nxb,
        const float* __restrict__ xrb, const unsigned short* __restrict__ an_b,
        const unsigned short* __restrict__ atn_b, const unsigned short* __restrict__ danr_b,
        const unsigned short* __restrict__ danc_b, const unsigned short* __restrict__ MeffB,
        const float* __restrict__ biasE, float* __restrict__ out) {
    __shared__ __align__(16) unsigned char smem[SMEM10];
    const int blk = blockIdx.x;
    const int b = blk / 96, l = blk % 96;
    const int t = threadIdx.x;
    const int wid = t >> 6, lane = t & 63, ln = lane & 31, half = lane >> 5;
    const bool act = (wid < 7);
    const int mt = wid;
    const int ocol0 = ln, ocol1 = 32 + ln;
    const int vr = mt * 32 + ln;
    const int ar = (vr < 200) ? vr : 0;
    const bool vz = (vr >= 200);

    const unsigned short* Achain[4] = { an_b, atn_b,
        danr_b + (size_t)blk * 41600, danc_b + (size_t)blk * 41600 };

    uint4 h0f[4] = {};
    if (act && !vz) {
        const unsigned short* H0p = nxb + (size_t)blk * 12800 + vr * 64;
#pragma unroll
        for (int kk = 0; kk < 4; kk++) {
            h0f[kk] = *(const uint4*)(const void*)(H0p + kk * 16 + half * 8);
        }
    }

    stageA(Achain[0], smem, t);
    if (t < 512) {
        int o = t >> 3, w = 200 + (t & 7);
        *(unsigned short*)(smem + OFF_HTA + ht4(o, w)) = 0;
        *(unsigned short*)(smem + OFF_HTB + ht4(o, w)) = 0;
    }
    __syncthreads();

    f32x16 ACC0 = {}, ACC1 = {};
    // pre-phase: ACC = H0@Mfold^T (both tiles) ; y2(chain0) serial per tile -> HTA
    if (act) {
        const unsigned short* MBf = MeffB;
        const unsigned short* MB2 = MeffB + 2 * 4096;
#pragma unroll
        for (int kk = 0; kk < 4; kk++) {
            const int c0 = kk * 16 + half * 8;
            bf16x8 h0 = __builtin_bit_cast(bf16x8, h0f[kk]);
            bf16x8 mf0 = __builtin_bit_cast(bf16x8, *(const uint4*)(const void*)(MBf + ocol0 * 64 + c0));
            ACC0 = __builtin_amdgcn_mfma_f32_32x32x16_bf16(h0, mf0, ACC0, 0, 0, 0);
            bf16x8 mf1 = __builtin_bit_cast(bf16x8, *(const uint4*)(const void*)(MBf + ocol1 * 64 + c0));
            ACC1 = __builtin_amdgcn_mfma_f32_32x32x16_bf16(h0, mf1, ACC1, 0, 0, 0);
        }
        {
            f32x16 y2 = {};
#pragma unroll
            for (int kk = 0; kk < 4; kk++) {
                const int c0 = kk * 16 + half * 8;
                bf16x8 m2 = __builtin_bit_cast(bf16x8, *(const uint4*)(const void*)(MB2 + ocol0 * 64 + c0));
                y2 = __builtin_amdgcn_mfma_f32_32x32x16_bf16(__builtin_bit_cast(bf16x8, h0f[kk]), m2, y2, 0, 0, 0);
            }
            store_tile_bf16(smem, OFF_HTA, y2, mt, ocol0, half);
        }
        {
            f32x16 y2 = {};
#pragma unroll
            for (int kk = 0; kk < 4; kk++) {
                const int c0 = kk * 16 + half * 8;
                bf16x8 m2 = __builtin_bit_cast(bf16x8, *(const uint4*)(const void*)(MB2 + ocol1 * 64 + c0));
                y2 = __builtin_amdgcn_mfma_f32_32x32x16_bf16(__builtin_bit_cast(bf16x8, h0f[kk]), m2, y2, 0, 0, 0);
            }
            store_tile_bf16(smem, OFF_HTA, y2, mt, ocol1, half);
        }
    }
    __syncthreads();

#pragma unroll 1
    for (int chain = 0; chain < 4; chain++) {
        // phase B: U = H0@N1^T + A@Y2(HTA) -> HTB  (both tiles, A-fragment shared)
        if (act) {
            const unsigned short* MB1 = MeffB + (size_t)(1 + 2 * chain) * 4096;
            f32x16 T0 = {}, T1 = {};
#pragma unroll
            for (int kk = 0; kk < 4; kk++) {
                const int c0 = kk * 16 + half * 8;
                bf16x8 h0 = __builtin_bit_cast(bf16x8, h0f[kk]);
                bf16x8 m10 = __builtin_bit_cast(bf16x8, *(const uint4*)(const void*)(MB1 + ocol0 * 64 + c0));
                T0 = __builtin_amdgcn_mfma_f32_32x32x16_bf16(h0, m10, T0, 0, 0, 0);
                bf16x8 m11 = __builtin_bit_cast(bf16x8, *(const uint4*)(const void*)(MB1 + ocol1 * 64 + c0));
                T1 = __builtin_amdgcn_mfma_f32_32x32x16_bf16(h0, m11, T1, 0, 0, 0);
            }
#pragma unroll
            for (int kk = 0; kk < 13; kk++) {
                const int k0 = kk * 16 + half * 8;
                uint4 av = *(const uint4*)(smem + OFF_A + (((2 * kk + half) * 200 + ar) << 4));
                if (vz) av = make_uint4(0, 0, 0, 0);
                bf16x8 a8 = __builtin_bit_cast(bf16x8, av);
                bf16x8 yb0 = __builtin_bit_cast(bf16x8, *(const uint4*)(smem + OFF_HTA + ht4(ocol0, k0)));
                T0 = __builtin_amdgcn_mfma_f32_32x32x16_bf16(a8, yb0, T0, 0, 0, 0);
                bf16x8 yb1 = __builtin_bit_cast(bf16x8, *(const uint4*)(smem + OFF_HTA + ht4(ocol1, k0)));
                T1 = __builtin_amdgcn_mfma_f32_32x32x16_bf16(a8, yb1, T1, 0, 0, 0);
            }
            store_tile_bf16(smem, OFF_HTB, T0, mt, ocol0, half);
            store_tile_bf16(smem, OFF_HTB, T1, mt, ocol1, half);
        }
        __syncthreads();
        // phase C: ACC += A@U(HTB) (both tiles)
        if (act) {
#pragma unroll
            for (int kk = 0; kk < 13; kk++) {
                const int k0 = kk * 16 + half * 8;
                uint4 av = *(const uint4*)(smem + OFF_A + (((2 * kk + half) * 200 + ar) << 4));
                if (vz) av = make_uint4(0, 0, 0, 0);
                bf16x8 a8 = __builtin_bit_cast(bf16x8, av);
                bf16x8 ub0 = __builtin_bit_cast(bf16x8, *(const uint4*)(smem + OFF_HTB + ht4(ocol0, k0)));
                ACC0 = __builtin_amdgcn_mfma_f32_32x32x16_bf16(a8, ub0, ACC0, 0, 0, 0);
                bf16x8 ub1 = __builtin_bit_cast(bf16x8, *(const uint4*)(smem + OFF_HTB + ht4(ocol1, k0)));
                ACC1 = __builtin_amdgcn_mfma_f32_32x32x16_bf16(a8, ub1, ACC1, 0, 0, 0);
            }
        }
        __syncthreads();
        if (chain < 3) {
            stageA(Achain[chain + 1], smem, t);
            if (act) {
                const unsigned short* MB2n = MeffB + (size_t)(4 + 2 * chain) * 4096;
                {
                    f32x16 y2 = {};
#pragma unroll
                    for (int kk = 0; kk < 4; kk++) {
                        const int c0 = kk * 16 + half * 8;
                        bf16x8 m2 = __builtin_bit_cast(bf16x8, *(const uint4*)(const void*)(MB2n + ocol0 * 64 + c0));
                        y2 = __builtin_amdgcn_mfma_f32_32x32x16_bf16(__builtin_bit_cast(bf16x8, h0f[kk]), m2, y2, 0, 0, 0);
                    }
                    store_tile_bf16(smem, OFF_HTA, y2, mt, ocol0, half);
                }
                {
                    f32x16 y2 = {};
#pragma unroll
                    for (int kk = 0; kk < 4; kk++) {
                        const int c0 = kk * 16 + half * 8;
                        bf16x8 m2 = __builtin_bit_cast(bf16x8, *(const uint4*)(const void*)(MB2n + ocol1 * 64 + c0));
                        y2 = __builtin_amdgcn_mfma_f32_32x32x16_bf16(__builtin_bit_cast(bf16x8, h0f[kk]), m2, y2, 0, 0, 0);
                    }
                    store_tile_bf16(smem, OFF_HTA, y2, mt, ocol1, half);
                }
            }
            __syncthreads();
        }
    }

    __syncthreads();
    if (act) {
#pragma unroll
        for (int r = 0; r < 16; r++) {
            const int v = mt * 32 + half * 4 + (r & 3) + (r >> 2) * 8;
            if (v < 200) *(float*)(smem + OFF_OBUF + (v * 64 + ocol0) * 4) = ACC0[r];
        }
#pragma unroll
        for (int r = 0; r < 16; r++) {
            const int v = mt * 32 + half * 4 + (r & 3) + (r >> 2) * 8;
            if (v < 200) *(float*)(smem + OFF_OBUF + (v * 64 + ocol1) * 4) = ACC1[r];
        }
    }
    __syncthreads();

    const size_t gbase = ((size_t)b * 200 * 96 + l) * 64;
    for (int idx = t; idx < 12800; idx += 1024) {
        int v = idx >> 6, o = idx & 63;
        float val = *(const float*)(smem + OFF_OBUF + idx * 4) + biasE[o];
        size_t gi = gbase + (size_t)v * 6144 + o;
        out[gi] = val + xrb[gi];
    }
}

extern "C" void kernel_launch(void* const* d_in, const int* in_sizes, int n_in,
                              void* d_out, int out_size, void* d_ws, size_t ws_size,
                              hipStream_t stream) {
    (void)in_sizes; (void)n_in; (void)out_size; (void)ws_size;
    const float* x    = (const float*)d_in[0];
    const float* adj  = (const float*)d_in[1];
    const float* dyna = (const float*)d_in[2];
    const float* g1   = (const float*)d_in[3];
    const float* b1   = (const float*)d_in[4];
    const float* g2   = (const float*)d_in[5];
    const float* b2   = (const float*)d_in[6];
    const float* Wih  = (const float*)d_in[7];
    const float* Whh  = (const float*)d_in[8];
    const float* bih  = (const float*)d_in[9];
    const float* bhh  = (const float*)d_in[10];
    const float* Wg1  = (const float*)d_in[11];
    const float* bg1  = (const float*)d_in[12];
    const float* Wg2  = (const float*)d_in[13];
    const float* bg2  = (const float*)d_in[14];
    const float* Wd1  = (const float*)d_in[15];
    const float* bd1  = (const float*)d_in[16];
    const float* Wd2  = (const float*)d_in[17];
    const float* bd2  = (const float*)d_in[18];
    const float* Wm   = (const float*)d_in[19];
    const float* bm   = (const float*)d_in[20];
    float* out = (float*)d_out;
    float* ws = (float*)d_ws;

    float*          xr    = ws;                                   // 9,830,400
    unsigned short* nxb   = (unsigned short*)(ws + 9830400);      // 9,830,400 bf16
    float*          g2t   = ws + 14745600;
    float*          b2t   = ws + 15974400;
    unsigned short* an_b  = (unsigned short*)(ws + 17203200);
    unsigned short* atn_b = (unsigned short*)(ws + 17226496);
    unsigned short* MeffB = (unsigned short*)(ws + 17249792);
    float*          biasE = ws + 17268224;
    float2*         s1p   = (float2*)(ws + 17268288);
    float2*         s1    = (float2*)(ws + 17269488);
    float2*         s2p   = (float2*)(ws + 17269504);
    float2*         s2    = (float2*)(ws + 17269904);
    float*          MeffF = ws + 17269920;
    unsigned short* danr_b = (unsigned short*)(ws + 17306784);
    unsigned short* danc_b = danr_b + 31953792;

    k_ln_part<<<dim3(75, 8), dim3(256), 0, stream>>>((const float4*)x, s1p);
    k_ln_final<<<dim3(8), dim3(64), 0, stream>>>(s1p, 75, s1);
    k_gru3<<<dim3(200), dim3(512), 0, stream>>>(x, g1, b1, s1, Wih, Whh, bih, bhh, xr, s2p);
    k_ln_final<<<dim3(8), dim3(64), 0, stream>>>(s2p, 25, s2);
    k_tr<<<dim3(200, 6), dim3(256), 0, stream>>>(g2, g2t);
    k_tr<<<dim3(200, 6), dim3(256), 0, stream>>>(b2, b2t);
    k_adjprep2<<<dim3(200, 2), dim3(256), 0, stream>>>(adj, an_b, atn_b);
    k_meff<<<dim3(9), dim3(256), 0, stream>>>(Wm, Wg1, Wg2, Wd1, Wd2, bg1, bg2, bd1, bd2, bm, MeffF, biasE);
    k_meffc<<<dim3(1), dim3(256), 0, stream>>>(MeffF, MeffB);
    k_nx<<<dim3(9600), dim3(256), 0, stream>>>((const float4*)xr, s2, (const float4*)g2t, (const float4*)b2t, nxb);
    k_dprep5<<<dim3(768), dim3(1024), 0, stream>>>(dyna, danr_b, danc_b);
    k_graph12<<<dim3(768), dim3(1024), 0, stream>>>(nxb, xr, an_b, atn_b, danr_b, danc_b, MeffB, biasE, out);
}

// Round 17
// 404.050 us; speedup vs baseline: 1.0984x; 1.0984x over previous
//
#include <hip/hip_runtime.h>
#include <math.h>

#define ALPHA_ 0.1f
#define BETA_  0.9f
#define EPS_   1e-5f

typedef __bf16 bf16x8 __attribute__((ext_vector_type(8)));
typedef float f32x16 __attribute__((ext_vector_type(16)));

__device__ __forceinline__ unsigned short f2bf(float f) {
    return __builtin_bit_cast(unsigned short, (__bf16)f);
}
__device__ __forceinline__ float bf2f(unsigned short u) {
    return (float)__builtin_bit_cast(__bf16, u);
}

__device__ __forceinline__ float wave_reduce_sum(float v) {
#pragma unroll
    for (int off = 32; off > 0; off >>= 1) v += __shfl_down(v, off, 64);
    return v;
}

// ---------------- LN partial sums (per-b mean/var, stage 1) ----------------
__global__ void k_ln_part(const float4* __restrict__ x4, float2* __restrict__ part) {
    const int b = blockIdx.y, jb = blockIdx.x, t = threadIdx.x;
    const size_t base = (size_t)b * 307200 + (size_t)jb * 4096;
    float s = 0.f, sq = 0.f;
#pragma unroll
    for (int k = 0; k < 16; k++) {
        float4 v = x4[base + k * 256 + t];
        s  += v.x + v.y + v.z + v.w;
        sq += v.x * v.x + v.y * v.y + v.z * v.z + v.w * v.w;
    }
    float rs = wave_reduce_sum(s);
    float rq = wave_reduce_sum(sq);
    __shared__ float2 ws[4];
    if ((t & 63) == 0) ws[t >> 6] = make_float2(rs, rq);
    __syncthreads();
    if (t == 0) {
        float a = 0.f, q = 0.f;
        for (int k = 0; k < 4; k++) { a += ws[k].x; q += ws[k].y; }
        part[b * 75 + jb] = make_float2(a, q);
    }
}

__global__ void k_ln_final(const float2* __restrict__ part, int nper, float2* __restrict__ outp) {
    const int b = blockIdx.x, t = threadIdx.x;
    float s = 0.f, sq = 0.f;
    for (int p = t; p < nper; p += 64) {
        float2 v = part[b * nper + p];
        s += v.x; sq += v.y;
    }
    s  = wave_reduce_sum(s);
    sq = wave_reduce_sum(sq);
    if (t == 0) {
        const float invN = 1.f / 1228800.f;
        float mu  = s * invN;
        float var = sq * invN - mu * mu;
        outp[b] = make_float2(mu, rsqrtf(var + EPS_));
    }
}

// ---------------- fused GRU: LN1 + input proj + recurrence ----------------
__global__ __launch_bounds__(512) void k_gru3(const float* __restrict__ x,
        const float* __restrict__ g1, const float* __restrict__ b1,
        const float2* __restrict__ s1, const float* __restrict__ Wih,
        const float* __restrict__ Whh, const float* __restrict__ bih,
        const float* __restrict__ bhh, float* __restrict__ xr, float2* __restrict__ s2p) {
    __shared__ unsigned short hb[32 * 128];
    __shared__ float gh[8 * 192];
    __shared__ float ghn[8 * 64];
    __shared__ float2 sRed[8];
    const int t = threadIdx.x;
    const int wid = t >> 6, lane = t & 63, ln = lane & 31, hl = lane >> 5;
    const int row0 = blockIdx.x * 8;
    const int r = wid;
    const int c = t & 63;
    const int row = row0 + r;
    const int sd = row % 200;
    const int bidx = row / 200;
    const bool isN = (wid >= 4 && wid < 6);

    bf16x8 Bf[8];
    if (wid < 6) {
        const int j = wid * 32 + ln;
#pragma unroll
        for (int ks = 0; ks < 8; ks++) {
            const float* Wsrc = (ks < 4) ? Wih : Whh;
            const int kk = (ks & 3) * 16 + hl * 8;
            const float* wp = Wsrc + j * 64 + kk;
            float4 w0 = *(const float4*)wp;
            float4 w1 = *(const float4*)(wp + 4);
            bf16x8 bb;
            bb[0] = (__bf16)w0.x; bb[1] = (__bf16)w0.y; bb[2] = (__bf16)w0.z; bb[3] = (__bf16)w0.w;
            bb[4] = (__bf16)w1.x; bb[5] = (__bf16)w1.y; bb[6] = (__bf16)w1.z; bb[7] = (__bf16)w1.w;
            Bf[ks] = bb;
        }
    }
    for (int i = t; i < 4096; i += 512) hb[i] = 0;
    __syncthreads();

    const float b_r = bih[c] + bhh[c];
    const float b_z = bih[64 + c] + bhh[64 + c];
    const float bx_n = bih[128 + c];
    const float bh_n = bhh[128 + c];
    const float2 st1 = s1[bidx];
    const float* xp  = x  + (size_t)row * 96 * 64;
    const float* gp  = g1 + (size_t)sd * 96 * 64;
    const float* bp  = b1 + (size_t)sd * 96 * 64;
    float*       xrp = xr + (size_t)row * 96 * 64;

    float xv = xp[c];
    {
        float xln = (xv - st1.x) * st1.y * gp[c] + bp[c];
        *(unsigned short*)((char*)hb + ((r * 256 + c * 2) ^ ((r & 7) << 4))) = f2bf(xln);
    }
    float h = 0.f, lsum = 0.f, lsq = 0.f;
    __syncthreads();

    for (int st = 0; st < 96; st++) {
        if (wid < 4) {
            f32x16 acc = {};
#pragma unroll
            for (int ks = 0; ks < 8; ks++) {
                int ao = (ln * 256 + ks * 32 + hl * 16) ^ ((ln & 7) << 4);
                bf16x8 af = __builtin_bit_cast(bf16x8, *(const uint4*)((const char*)hb + ao));
                acc = __builtin_amdgcn_mfma_f32_32x32x16_bf16(af, Bf[ks], acc, 0, 0, 0);
            }
#pragma unroll
            for (int reg = 0; reg < 4; reg++)
                gh[(reg + 4 * hl) * 192 + wid * 32 + ln] = acc[reg];
        } else if (isN) {
            f32x16 accx = {}, acch = {};
#pragma unroll
            for (int ks = 0; ks < 4; ks++) {
                int aox = (ln * 256 + ks * 32 + hl * 16) ^ ((ln & 7) << 4);
                bf16x8 afx = __builtin_bit_cast(bf16x8, *(const uint4*)((const char*)hb + aox));
                accx = __builtin_amdgcn_mfma_f32_32x32x16_bf16(afx, Bf[ks], accx, 0, 0, 0);
                int aoh = (ln * 256 + (ks + 4) * 32 + hl * 16) ^ ((ln & 7) << 4);
                bf16x8 afh = __builtin_bit_cast(bf16x8, *(const uint4*)((const char*)hb + aoh));
                acch = __builtin_amdgcn_mfma_f32_32x32x16_bf16(afh, Bf[ks + 4], acch, 0, 0, 0);
            }
#pragma unroll
            for (int reg = 0; reg < 4; reg++) {
                gh[(reg + 4 * hl) * 192 + wid * 32 + ln] = accx[reg];
                ghn[(reg + 4 * hl) * 64 + (wid - 4) * 32 + ln] = acch[reg];
            }
        }
        int sn = st < 95 ? st + 1 : 95;
        float xv_n = xp[sn * 64 + c];
        float g1_n = gp[sn * 64 + c];
        float b1_n = bp[sn * 64 + c];
        __syncthreads();
        float rg_ = 1.f / (1.f + __expf(-(gh[r * 192 + c] + b_r)));
        float zg_ = 1.f / (1.f + __expf(-(gh[r * 192 + 64 + c] + b_z)));
        float xn = gh[r * 192 + 128 + c] + bx_n;
        float hn = ghn[r * 64 + c] + bh_n;
        float ny = xn + rg_ * hn;
        ny = fminf(fmaxf(ny, -15.f), 15.f);
        float e2 = __expf(-2.f * ny);
        float nv = (1.f - e2) / (1.f + e2);
        h = nv + zg_ * (h - nv);
        float ov = h + xv;
        xrp[st * 64 + c] = ov;
        lsum += ov; lsq += ov * ov;
        *(unsigned short*)((char*)hb + ((r * 256 + (64 + c) * 2) ^ ((r & 7) << 4))) = f2bf(h);
        float xln = (xv_n - st1.x) * st1.y * g1_n + b1_n;
        *(unsigned short*)((char*)hb + ((r * 256 + c * 2) ^ ((r & 7) << 4))) = f2bf(xln);
        xv = xv_n;
        __syncthreads();
    }
    float s = wave_reduce_sum(lsum);
    float q = wave_reduce_sum(lsq);
    if (lane == 0) sRed[wid] = make_float2(s, q);
    __syncthreads();
    if (t == 0) {
        float a = 0.f, b_ = 0.f;
        for (int k = 0; k < 8; k++) { a += sRed[k].x; b_ += sRed[k].y; }
        s2p[blockIdx.x] = make_float2(a, b_);
    }
}

// ---------------- transpose g2/b2: [64][200][96] -> [96][200][64] ----------------
__global__ void k_tr(const float* __restrict__ in, float* __restrict__ outp) {
    __shared__ float tile[32][33];
    const int v = blockIdx.x;
    const int ct = blockIdx.y & 1;
    const int lt = blockIdx.y >> 1;
    const int t = threadIdx.x;
    const int lx = t & 31, ly = t >> 5;
    const int c0 = ct * 32, l0 = lt * 32;
#pragma unroll
    for (int q = 0; q < 4; q++) {
        int cc = ly + q * 8;
        tile[cc][lx] = in[(size_t)(c0 + cc) * 19200 + (size_t)v * 96 + l0 + lx];
    }
    __syncthreads();
#pragma unroll
    for (int q = 0; q < 4; q++) {
        int ll = ly + q * 8;
        outp[(size_t)(l0 + ll) * 12800 + (size_t)v * 64 + c0 + lx] = tile[lx][ll];
    }
}

// ---------------- static adjacency -> normalized bf16, chunk-major [26][200][8] ----------------
__global__ void k_adjprep2(const float* __restrict__ adj, unsigned short* __restrict__ an_b,
        unsigned short* __restrict__ atn_b) {
    const int v = blockIdx.x;
    const int mode = blockIdx.y;
    const int t = threadIdx.x;
    unsigned short* outp = (mode == 0) ? an_b : atn_b;
    float val = 0.f;
    if (t < 200) val = (mode == 0) ? adj[v * 200 + t] : adj[t * 200 + v];
    float s = wave_reduce_sum(val);
    __shared__ float sp[4];
    if ((t & 63) == 0) sp[t >> 6] = s;
    __syncthreads();
    float inv = 1.f / (sp[0] + sp[1] + sp[2] + sp[3] + 1.f);
    if (t < 208) {
        float o = (t < 200) ? (val + (t == v ? 1.f : 0.f)) * inv : 0.f;
        outp[(((t >> 3) * 200) + v) * 8 + (t & 7)] = f2bf(o);
    }
}

// ---------------- dyna prep v5: 1024 threads, chunk-major output ----------------
__global__ __launch_bounds__(1024) void k_dprep5(const float* __restrict__ dyna,
        unsigned short* __restrict__ danr, unsigned short* __restrict__ danc) {
    __shared__ unsigned short sT[200 * 201];
    __shared__ float sRow[200];
    __shared__ float sColP[16][256];
    __shared__ float sInv[416];
    const int blk = blockIdx.x;
    const int t = threadIdx.x;
    const int lane = t & 63, rq = t >> 6;
    const float* S = dyna + (size_t)blk * 40000;
    float colacc[4] = {0.f, 0.f, 0.f, 0.f};
    for (int p = 0; p < 13; p++) {
        const int r = p * 16 + rq;
        if (r < 200) {
            float rsum = 0.f;
#pragma unroll
            for (int s = 0; s < 4; s++) {
                const int c = s * 64 + lane;
                if (c < 200) {
                    float v = S[r * 200 + c] + ((r == c) ? 1.f : 0.f);
                    sT[c * 201 + r] = f2bf(v);
                    rsum += v;
                    colacc[s] += v;
                }
            }
            float rs = wave_reduce_sum(rsum);
            if (lane == 0) sRow[r] = rs;
        }
    }
#pragma unroll
    for (int s = 0; s < 4; s++) sColP[rq][s * 64 + lane] = colacc[s];
    __syncthreads();
    if (t < 200) {
        sInv[t] = 1.f / sRow[t];
        float cs = 0.f;
#pragma unroll
        for (int q = 0; q < 16; q++) cs += sColP[q][t];
        sInv[208 + t] = 1.f / cs;
    }
    __syncthreads();
    unsigned short* dr = danr + (size_t)blk * 41600;
    unsigned short* dc = danc + (size_t)blk * 41600;
    for (int item = t; item < 5200; item += 1024) {
        const int cch = item / 200;
        const int v = item - cch * 200;
        const float irv = sInv[v];
        const float icv = sInv[208 + v];
        unsigned short rb[8], cb[8];
#pragma unroll
        for (int j = 0; j < 8; j++) {
            const int w = cch * 8 + j;
            float fr = 0.f, fc = 0.f;
            if (w < 200) {
                fr = bf2f(sT[w * 201 + v]) * irv;
                fc = bf2f(sT[v * 201 + w]) * icv;
            }
            rb[j] = f2bf(fr); cb[j] = f2bf(fc);
        }
        *(uint4*)&dr[item * 8] = make_uint4(
            (unsigned)rb[0] | ((unsigned)rb[1] << 16), (unsigned)rb[2] | ((unsigned)rb[3] << 16),
            (unsigned)rb[4] | ((unsigned)rb[5] << 16), (unsigned)rb[6] | ((unsigned)rb[7] << 16));
        *(uint4*)&dc[item * 8] = make_uint4(
            (unsigned)cb[0] | ((unsigned)cb[1] << 16), (unsigned)cb[2] | ((unsigned)cb[3] << 16),
            (unsigned)cb[4] | ((unsigned)cb[5] << 16), (unsigned)cb[6] | ((unsigned)cb[7] << 16));
    }
}

// ---------------- effective projection matrices (f32 scratch) + biasE ----------------
__global__ void k_meff(const float* __restrict__ Wm, const float* __restrict__ Wg1,
        const float* __restrict__ Wg2, const float* __restrict__ Wd1, const float* __restrict__ Wd2,
        const float* __restrict__ bg1, const float* __restrict__ bg2, const float* __restrict__ bd1,
        const float* __restrict__ bd2, const float* __restrict__ bm,
        float* __restrict__ MeffF, float* __restrict__ biasE) {
    const int k = blockIdx.x;
    const int t = threadIdx.x;
    const int o = t >> 2;
    const int cb = (t & 3) * 16;
    float acc[16];
#pragma unroll
    for (int q = 0; q < 16; q++) acc[q] = 0.f;
    if (k == 0) {
        for (int m = 0; m < 64; m++) {
            float aL = Wm[o * 128 + m], aR = Wm[o * 128 + 64 + m];
#pragma unroll
            for (int q = 0; q < 16; q++) {
                int cc = cb + q;
                acc[q] += aL * (Wg1[m * 192 + cc] + Wg2[m * 192 + cc])
                        + aR * (Wd1[m * 192 + cc] + Wd2[m * 192 + cc]);
            }
        }
    } else {
        const float* Ws = (k <= 2) ? Wg1 : (k <= 4) ? Wg2 : (k <= 6) ? Wd1 : Wd2;
        const int side = (k <= 4) ? 0 : 64;
        const int hop = (((k - 1) & 1) == 0) ? 64 : 128;
        for (int m = 0; m < 64; m++) {
            float a_ = Wm[o * 128 + side + m];
#pragma unroll
            for (int q = 0; q < 16; q++) acc[q] += a_ * Ws[m * 192 + hop + cb + q];
        }
    }
#pragma unroll
    for (int q = 0; q < 16; q++) MeffF[k * 4096 + o * 64 + cb + q] = acc[q];
    if (k == 0 && t < 64) {
        float s = bm[t];
        for (int cc = 0; cc < 64; cc++)
            s += Wm[t * 128 + cc] * (bg1[cc] + bg2[cc]) + Wm[t * 128 + 64 + cc] * (bd1[cc] + bd2[cc]);
        biasE[t] = s;
    }
}

// ---------------- combine: M_fold / N1 / N2 -> bf16 MeffB[9][4096] ----------------
__global__ void k_meffc(const float* __restrict__ MeffF, unsigned short* __restrict__ MeffB) {
    const int t = threadIdx.x;
#pragma unroll 4
    for (int j = 0; j < 16; j++) {
        int idx = t * 16 + j;
        float m[9];
#pragma unroll
        for (int k = 0; k < 9; k++) m[k] = MeffF[k * 4096 + idx];
        float sum = 0.f;
#pragma unroll
        for (int k = 1; k < 9; k++) sum += m[k];
        MeffB[idx] = f2bf(m[0] + ALPHA_ * sum);
#pragma unroll
        for (int c = 0; c < 4; c++) {
            MeffB[(1 + 2 * c) * 4096 + idx] = f2bf(BETA_ * m[1 + 2 * c] + ALPHA_ * BETA_ * m[2 + 2 * c]);
            MeffB[(2 + 2 * c) * 4096 + idx] = f2bf(BETA_ * BETA_ * m[2 + 2 * c]);
        }
    }
}

// ---------------- nx (bf16) = LN2(xr), layout [b*96+l][v][c] ----------------
__global__ void k_nx(const float4* __restrict__ xr4, const float2* __restrict__ s2,
        const float4* __restrict__ g2t4, const float4* __restrict__ b2t4,
        unsigned short* __restrict__ nxb) {
    size_t id = (size_t)blockIdx.x * 256 + threadIdx.x;
    int cf = (int)(id & 15);
    size_t grp = id >> 4;
    int v = (int)(grp % 200);
    size_t bl = grp / 200;
    int l = (int)(bl % 96);
    int b = (int)(bl / 96);
    float2 st = s2[b];
    float4 xv = xr4[(((size_t)(b * 200 + v)) * 96 + l) * 16 + cf];
    size_t gi = ((size_t)l * 200 + v) * 16 + cf;
    float4 g = g2t4[gi];
    float4 bb = b2t4[gi];
    unsigned int lo = (unsigned)f2bf((xv.x - st.x) * st.y * g.x + bb.x)
                    | ((unsigned)f2bf((xv.y - st.x) * st.y * g.y + bb.y) << 16);
    unsigned int hi = (unsigned)f2bf((xv.z - st.x) * st.y * g.z + bb.z)
                    | ((unsigned)f2bf((xv.w - st.x) * st.y * g.w + bb.w) << 16);
    ((uint2*)nxb)[id] = make_uint2(lo, hi);
}

// ================= MFMA graph kernel v10b (frozen, 133us verified x3) =================
#define OFF_A 0
#define OFF_HTA 83968
#define OFF_HTB 110592
#define OFF_OBUF 0
#define SMEM10 137216

__device__ __forceinline__ int ht4(int o, int w) {
    return (o * 416 + w * 2) ^ ((o & 7) << 4);
}

__device__ __forceinline__ void store_tile_bf16(unsigned char* smem, int off, const f32x16& val,
        int mt, int ocol, int half) {
#pragma unroll
    for (int g = 0; g < 4; g++) {
        const int wv = mt * 32 + half * 4 + g * 8;
        if (wv < 200) {
            unsigned short pk[4];
#pragma unroll
            for (int i = 0; i < 4; i++) pk[i] = f2bf(val[g * 4 + i]);
            *(uint2*)(smem + off + ht4(ocol, wv)) = make_uint2(
                (unsigned)pk[0] | ((unsigned)pk[1] << 16),
                (unsigned)pk[2] | ((unsigned)pk[3] << 16));
        }
    }
}

__device__ __forceinline__ void stageA(const unsigned short* __restrict__ A,
        unsigned char* smem, int t) {
#pragma unroll
    for (int i = 0; i < 5; i++) {
        const int idx = t + i * 1024;
        __builtin_amdgcn_global_load_lds(
            (const __attribute__((address_space(1))) unsigned int*)(const void*)(A + (size_t)idx * 8),
            (__attribute__((address_space(3))) unsigned int*)(void*)(smem + OFF_A + idx * 16),
            16, 0, 0);
    }
    if (t < 80) {
        const int idx = 5120 + t;
        *(uint4*)(smem + OFF_A + idx * 16) = *(const uint4*)(const void*)(A + (size_t)idx * 8);
    }
}

__global__ __launch_bounds__(1024) void k_graph10(const unsigned short* __restrict__ nxb,
        const float* __restrict__ xrb, const unsigned short* __restrict__ an_b,
        const unsigned short* __restrict__ atn_b, const unsigned short* __restrict__ danr_b,
        const unsigned short* __restrict__ danc_b, const unsigned short* __restrict__ MeffB,
        const float* __restrict__ biasE, float* __restrict__ out) {
    __shared__ __align__(16) unsigned char smem[SMEM10];
    const int blk = blockIdx.x;
    const int b = blk / 96, l = blk % 96;
    const int t = threadIdx.x;
    const int wid = t >> 6, lane = t & 63, ln = lane & 31, half = lane >> 5;
    const bool act = (wid < 14);
    const int mt = wid >> 1, ot = wid & 1;
    const int ocol = ot * 32 + ln;
    const int vr = mt * 32 + ln;
    const int ar = (vr < 200) ? vr : 0;
    const bool vz = (vr >= 200);

    const unsigned short* Achain[4] = { an_b, atn_b,
        danr_b + (size_t)blk * 41600, danc_b + (size_t)blk * 41600 };

    uint4 h0f[4] = {};
    if (act && !vz) {
        const unsigned short* H0p = nxb + (size_t)blk * 12800 + vr * 64;
#pragma unroll
        for (int kk = 0; kk < 4; kk++) {
            h0f[kk] = *(const uint4*)(const void*)(H0p + kk * 16 + half * 8);
        }
    }

    stageA(Achain[0], smem, t);
    if (t < 512) {
        int o = t >> 3, w = 200 + (t & 7);
        *(unsigned short*)(smem + OFF_HTA + ht4(o, w)) = 0;
        *(unsigned short*)(smem + OFF_HTB + ht4(o, w)) = 0;
    }
    __syncthreads();

    f32x16 ACC = {};
    if (act) {
        const unsigned short* MBf = MeffB;
        const unsigned short* MB2 = MeffB + 2 * 4096;
        f32x16 y2 = {};
#pragma unroll
        for (int kk = 0; kk < 4; kk++) {
            const int c0 = kk * 16 + half * 8;
            bf16x8 h0 = __builtin_bit_cast(bf16x8, h0f[kk]);
            bf16x8 mf = __builtin_bit_cast(bf16x8, *(const uint4*)(const void*)(MBf + ocol * 64 + c0));
            ACC = __builtin_amdgcn_mfma_f32_32x32x16_bf16(h0, mf, ACC, 0, 0, 0);
            bf16x8 m2 = __builtin_bit_cast(bf16x8, *(const uint4*)(const void*)(MB2 + ocol * 64 + c0));
            y2 = __builtin_amdgcn_mfma_f32_32x32x16_bf16(h0, m2, y2, 0, 0, 0);
        }
        store_tile_bf16(smem, OFF_HTA, y2, mt, ocol, half);
    }
    __syncthreads();

#pragma unroll 1
    for (int chain = 0; chain < 4; chain++) {
        if (act) {
            const unsigned short* MB1 = MeffB + (size_t)(1 + 2 * chain) * 4096;
            f32x16 T = {};
#pragma unroll
            for (int kk = 0; kk < 4; kk++) {
                const int c0 = kk * 16 + half * 8;
                bf16x8 h0 = __builtin_bit_cast(bf16x8, h0f[kk]);
                bf16x8 m1 = __builtin_bit_cast(bf16x8, *(const uint4*)(const void*)(MB1 + ocol * 64 + c0));
                T = __builtin_amdgcn_mfma_f32_32x32x16_bf16(h0, m1, T, 0, 0, 0);
            }
#pragma unroll
            for (int kk = 0; kk < 13; kk++) {
                const int k0 = kk * 16 + half * 8;
                uint4 av = *(const uint4*)(smem + OFF_A + (((2 * kk + half) * 200 + ar) << 4));
                if (vz) av = make_uint4(0, 0, 0, 0);
                bf16x8 yb = __builtin_bit_cast(bf16x8, *(const uint4*)(smem + OFF_HTA + ht4(ocol, k0)));
                T = __builtin_amdgcn_mfma_f32_32x32x16_bf16(
                    __builtin_bit_cast(bf16x8, av), yb, T, 0, 0, 0);
            }
            store_tile_bf16(smem, OFF_HTB, T, mt, ocol, half);
        }
        __syncthreads();
        if (act) {
#pragma unroll
            for (int kk = 0; kk < 13; kk++) {
                const int k0 = kk * 16 + half * 8;
                uint4 av = *(const uint4*)(smem + OFF_A + (((2 * kk + half) * 200 + ar) << 4));
                if (vz) av = make_uint4(0, 0, 0, 0);
                bf16x8 ub = __builtin_bit_cast(bf16x8, *(const uint4*)(smem + OFF_HTB + ht4(ocol, k0)));
                ACC = __builtin_amdgcn_mfma_f32_32x32x16_bf16(
                    __builtin_bit_cast(bf16x8, av), ub, ACC, 0, 0, 0);
            }
        }
        __syncthreads();
        if (chain < 3) {
            stageA(Achain[chain + 1], smem, t);
            if (act) {
                const unsigned short* MB2n = MeffB + (size_t)(4 + 2 * chain) * 4096;
                f32x16 y2 = {};
#pragma unroll
                for (int kk = 0; kk < 4; kk++) {
                    const int c0 = kk * 16 + half * 8;
                    bf16x8 h0 = __builtin_bit_cast(bf16x8, h0f[kk]);
                    bf16x8 m2 = __builtin_bit_cast(bf16x8, *(const uint4*)(const void*)(MB2n + ocol * 64 + c0));
                    y2 = __builtin_amdgcn_mfma_f32_32x32x16_bf16(h0, m2, y2, 0, 0, 0);
                }
                store_tile_bf16(smem, OFF_HTA, y2, mt, ocol, half);
            }
            __syncthreads();
        }
    }

    __syncthreads();
    if (act) {
#pragma unroll
        for (int r = 0; r < 16; r++) {
            const int v = mt * 32 + half * 4 + (r & 3) + (r >> 2) * 8;
            if (v < 200) *(float*)(smem + OFF_OBUF + (v * 64 + ocol) * 4) = ACC[r];
        }
    }
    __syncthreads();

    const size_t gbase = ((size_t)b * 200 * 96 + l) * 64;
    for (int idx = t; idx < 12800; idx += 1024) {
        int v = idx >> 6, o = idx & 63;
        float val = *(const float*)(smem + OFF_OBUF + idx * 4) + biasE[o];
        size_t gi = gbase + (size_t)v * 6144 + o;
        out[gi] = val + xrb[gi];
    }
}

extern "C" void kernel_launch(void* const* d_in, const int* in_sizes, int n_in,
                              void* d_out, int out_size, void* d_ws, size_t ws_size,
                              hipStream_t stream) {
    (void)in_sizes; (void)n_in; (void)out_size; (void)ws_size;
    const float* x    = (const float*)d_in[0];
    const float* adj  = (const float*)d_in[1];
    const float* dyna = (const float*)d_in[2];
    const float* g1   = (const float*)d_in[3];
    const float* b1   = (const float*)d_in[4];
    const float* g2   = (const float*)d_in[5];
    const float* b2   = (const float*)d_in[6];
    const float* Wih  = (const float*)d_in[7];
    const float* Whh  = (const float*)d_in[8];
    const float* bih  = (const float*)d_in[9];
    const float* bhh  = (const float*)d_in[10];
    const float* Wg1  = (const float*)d_in[11];
    const float* bg1  = (const float*)d_in[12];
    const float* Wg2  = (const float*)d_in[13];
    const float* bg2  = (const float*)d_in[14];
    const float* Wd1  = (const float*)d_in[15];
    const float* bd1  = (const float*)d_in[16];
    const float* Wd2  = (const float*)d_in[17];
    const float* bd2  = (const float*)d_in[18];
    const float* Wm   = (const float*)d_in[19];
    const float* bm   = (const float*)d_in[20];
    float* out = (float*)d_out;
    float* ws = (float*)d_ws;

    float*          xr    = ws;                                   // 9,830,400
    unsigned short* nxb   = (unsigned short*)(ws + 9830400);      // 9,830,400 bf16
    float*          g2t   = ws + 14745600;
    float*          b2t   = ws + 15974400;
    unsigned short* an_b  = (unsigned short*)(ws + 17203200);
    unsigned short* atn_b = (unsigned short*)(ws + 17226496);
    unsigned short* MeffB = (unsigned short*)(ws + 17249792);
    float*          biasE = ws + 17268224;
    float2*         s1p   = (float2*)(ws + 17268288);
    float2*         s1    = (float2*)(ws + 17269488);
    float2*         s2p   = (float2*)(ws + 17269504);
    float2*         s2    = (float2*)(ws + 17269904);
    float*          MeffF = ws + 17269920;
    unsigned short* danr_b = (unsigned short*)(ws + 17306784);
    unsigned short* danc_b = danr_b + 31953792;

    k_ln_part<<<dim3(75, 8), dim3(256), 0, stream>>>((const float4*)x, s1p);
    k_ln_final<<<dim3(8), dim3(64), 0, stream>>>(s1p, 75, s1);
    k_gru3<<<dim3(200), dim3(512), 0, stream>>>(x, g1, b1, s1, Wih, Whh, bih, bhh, xr, s2p);
    k_ln_final<<<dim3(8), dim3(64), 0, stream>>>(s2p, 25, s2);
    k_tr<<<dim3(200, 6), dim3(256), 0, stream>>>(g2, g2t);
    k_tr<<<dim3(200, 6), dim3(256), 0, stream>>>(b2, b2t);
    k_adjprep2<<<dim3(200, 2), dim3(256), 0, stream>>>(adj, an_b, atn_b);
    k_meff<<<dim3(9), dim3(256), 0, stream>>>(Wm, Wg1, Wg2, Wd1, Wd2, bg1, bg2, bd1, bd2, bm, MeffF, biasE);
    k_meffc<<<dim3(1), dim3(256), 0, stream>>>(MeffF, MeffB);
    k_nx<<<dim3(9600), dim3(256), 0, stream>>>((const float4*)xr, s2, (const float4*)g2t, (const float4*)b2t, nxb);
    k_dprep5<<<dim3(768), dim3(1024), 0, stream>>>(dyna, danr_b, danc_b);
    k_graph10<<<dim3(768), dim3(1024), 0, stream>>>(nxb, xr, an_b, atn_b, danr_b, danc_b, MeffB, biasE, out);
}